// Round 17
// baseline (4801.302 us; speedup 1.0000x reference)
//
#include <hip/hip_runtime.h>

typedef _Float16 f16x8 __attribute__((ext_vector_type(8)));
typedef float f32x4 __attribute__((ext_vector_type(4)));

#define LOG2E 1.44269504088896340736f
#define MELEM 16          // batch elems per block (1 M-tile of 16)
#define HS 72             // f16 stride of h LDS rows (16B-aligned, bank-spread)
#define INV2K 4.8828125e-4f   // 2^-11
#define SC2K  2048.0f         // 2^11

__device__ __forceinline__ float bpermf(int sa, float v) {
    return __builtin_bit_cast(float,
        __builtin_amdgcn_ds_bpermute(sa, __builtin_bit_cast(int, v)));
}

// barrier that waits ONLY on LDS (lgkm), not on in-flight global traj stores
#define LDS_BARRIER() asm volatile("s_waitcnt lgkmcnt(0)\n\ts_barrier" ::: "memory")

// 4 waves/block, wave w owns unit group [16w,16w+16); block owns 16 batch elems.
// Register diet: head B-frags + z-dot scalars live in read-only LDS tables
// (re-read each step; barrier memory-clobber prevents hoisting) so the unified
// VGPR+AGPR total fits 4 waves/SIMD. Waves 1/2/3 store traj comps 0/1/2.
__global__ __launch_bounds__(256, 2)
void gru_mfma_kernel(const float* __restrict__ z0,
                     const float* __restrict__ dtp,
                     const int* __restrict__ stepsp,
                     const float* __restrict__ Wih,
                     const float* __restrict__ Whh,
                     const float* __restrict__ bih,
                     const float* __restrict__ bhh,
                     const float* __restrict__ Whead,
                     const float* __restrict__ bhead,
                     float* __restrict__ out)
{
    // [pingpong][part hi/lo][elem*HS + unit], fp16 2-way split of h  (9216 B)
    __shared__ _Float16 hbuf[2][2][MELEM*HS];
    // head B-fragments, one per lane-id (shared by all waves)        (4096 B)
    __shared__ __align__(16) f16x8 hdB[2][2][64];   // [part][kk][lane]
    // per-unit z-dot weights (prescaled), [unit][12] f32             (3072 B)
    __shared__ __align__(16) float wz[64][12];

    const int tid = threadIdx.x;
    const int w   = tid >> 6;       // wave 0..3 = unit group
    const int l   = tid & 63;
    const int c16 = l & 15;
    const int g   = l >> 4;         // 0..3
    const int unit = 16*w + c16;

    const float dtv = dtp[0];
    const int nsteps = stepsp[0];
    const size_t T3 = (size_t)(nsteps + 1) * 3;
    const long blk = blockIdx.x;

    // ---- B-fragments of W_hh: fp16 hi + 2^11-scaled lo, LOG2E-prescaled ----
    f16x8 WBh[3][2], WBl[3][2];
    #pragma unroll
    for (int gate = 0; gate < 3; ++gate) {
        const float gs = (gate == 2) ? 2.f*LOG2E : LOG2E;
        const float* row = Whh + (size_t)(gate*64 + unit) * 64;
        #pragma unroll
        for (int kk = 0; kk < 2; ++kk) {
            const float* p = row + 32*kk + 8*g;
            f16x8 bh_, bl_;
            #pragma unroll
            for (int j = 0; j < 8; ++j) {
                float x = gs * p[j];
                _Float16 hi = (_Float16)x;
                bh_[j] = hi;
                bl_[j] = (_Float16)((x - (float)hi) * SC2K);
            }
            WBh[gate][kk] = bh_;
            WBl[gate][kk] = bl_;
        }
    }
    // ---- head B-fragments -> LDS table (wave 0 fills; frag depends on l only) ----
    if (w == 0) {
        #pragma unroll
        for (int kk = 0; kk < 2; ++kk) {
            f16x8 bh_ = {0,0,0,0,0,0,0,0}, bl_ = {0,0,0,0,0,0,0,0};
            if (c16 < 3) {
                const float* p = Whead + (size_t)c16*64 + 32*kk + 8*g;
                #pragma unroll
                for (int j = 0; j < 8; ++j) {
                    float x = p[j];
                    _Float16 hi = (_Float16)x;
                    bh_[j] = hi;
                    bl_[j] = (_Float16)((x - (float)hi) * SC2K);
                }
            }
            hdB[0][kk][l] = bh_;
            hdB[1][kk][l] = bl_;
        }
    }
    // ---- z-dot scalar weights -> LDS table (one writer per unit: g==0) ----
    if (g == 0) {
        #pragma unroll
        for (int j = 0; j < 3; ++j) {
            wz[unit][0+j] = LOG2E     * Wih[(0*64+unit)*3 + j];
            wz[unit][3+j] = LOG2E     * Wih[(1*64+unit)*3 + j];
            wz[unit][6+j] = 2.f*LOG2E * Wih[(2*64+unit)*3 + j];
        }
        wz[unit][9] = 0.f; wz[unit][10] = 0.f; wz[unit][11] = 0.f;
    }

    // ---- per-lane biases (prescaled; stay in regs) ----
    const float br   = LOG2E*(bih[0*64+unit] + bhh[0*64+unit]);
    const float bu   = LOG2E*(bih[1*64+unit] + bhh[1*64+unit]);
    const float bin_ = 2.f*LOG2E*bih[2*64+unit];
    const float bhn  = 2.f*LOG2E*bhh[2*64+unit];
    float bhc = 0.f;
    if (c16 < 3) bhc = bhead[c16];

    // ---- z for the block's 16-elem tile, replicated across all lanes ----
    float zreg[4][3];
    #pragma unroll
    for (int r = 0; r < 4; ++r)
        #pragma unroll
        for (int c = 0; c < 3; ++c)
            zreg[r][c] = z0[(size_t)(blk*MELEM + 4*g + r)*3 + c];

    // ---- traj cursor: wave w in {1,2,3} stores comp w-1 via lanes c16==0 ----
    float* o0 = out;
    if (w != 0 && c16 == 0)
        o0 = out + (size_t)(blk*MELEM + 4*g)*T3 + (w - 1);

#define ZSTORE() do {                                                            \
    if (c16 == 0) {                                                              \
        if (w == 1) {                                                            \
            o0[0] = zreg[0][0]; o0[T3] = zreg[1][0];                              \
            o0[2*T3] = zreg[2][0]; o0[3*T3] = zreg[3][0];                         \
        } else if (w == 2) {                                                      \
            o0[0] = zreg[0][1]; o0[T3] = zreg[1][1];                              \
            o0[2*T3] = zreg[2][1]; o0[3*T3] = zreg[3][1];                         \
        } else if (w == 3) {                                                      \
            o0[0] = zreg[0][2]; o0[T3] = zreg[1][2];                              \
            o0[2*T3] = zreg[2][2]; o0[3*T3] = zreg[3][2];                         \
        }                                                                         \
    }                                                                             \
    o0 += 3;                                                                      \
} while (0)

    // t=0 row
    ZSTORE();   // -> cursor now at t=1

    // hoisted bpermute byte-addresses
    const int sa0 = (l & 48) << 2;
    const int sa1 = sa0 + 4;
    const int sa2 = sa0 + 8;

    // step-invariant LDS element offsets
    const int adA0 = c16*HS + 8*g;           // A-frag read row
    const int adW  = (4*g)*HS + unit;        // h write base (+ r*HS)

    // ---- zero h buffer 0 (h_0 = 0): 1152 dwords ----
    {
        uint* hz = (uint*)&hbuf[0][0][0];
        for (int i = tid; i < MELEM*HS; i += 256) hz[i] = 0u;
    }

    float hC[4] = {0.f,0.f,0.f,0.f};

    __syncthreads();

#define GATE(GT, GR, BIAS) do {                                                  \
    f32x4 a1 = {BIAS,BIAS,BIAS,BIAS}, a2 = {0.f,0.f,0.f,0.f};                    \
    a1 = __builtin_amdgcn_mfma_f32_16x16x32_f16(FAh0, WBh[GT][0], a1, 0,0,0);    \
    a2 = __builtin_amdgcn_mfma_f32_16x16x32_f16(FAh0, WBl[GT][0], a2, 0,0,0);    \
    a2 = __builtin_amdgcn_mfma_f32_16x16x32_f16(FAl0, WBh[GT][0], a2, 0,0,0);    \
    a1 = __builtin_amdgcn_mfma_f32_16x16x32_f16(FAh1, WBh[GT][1], a1, 0,0,0);    \
    a2 = __builtin_amdgcn_mfma_f32_16x16x32_f16(FAh1, WBl[GT][1], a2, 0,0,0);    \
    a2 = __builtin_amdgcn_mfma_f32_16x16x32_f16(FAl1, WBh[GT][1], a2, 0,0,0);    \
    _Pragma("unroll")                                                            \
    for (int rr = 0; rr < 4; ++rr) GR[rr] = __builtin_fmaf(INV2K, a2[rr], a1[rr]); \
} while (0)

#define STEP(P, DOZ) do {                                                        \
    f16x8 FAh0 = *(const f16x8*)&hbuf[P][0][adA0];                               \
    f16x8 FAh1 = *(const f16x8*)&hbuf[P][0][adA0 + 32];                          \
    f16x8 FAl0 = *(const f16x8*)&hbuf[P][1][adA0];                               \
    f16x8 FAl1 = *(const f16x8*)&hbuf[P][1][adA0 + 32];                          \
    f32x4 wA = *(const f32x4*)&wz[unit][0];  /* wir0,1,2, wiu0 */                \
    f32x4 wB = *(const f32x4*)&wz[unit][4];  /* wiu1,2, win0,1 */                \
    float  wC = wz[unit][8];                 /* win2 */                          \
    if (DOZ) {                                                                   \
        f16x8 Hh0 = hdB[0][0][l]; f16x8 Hh1 = hdB[0][1][l];                      \
        f16x8 Hl0 = hdB[1][0][l]; f16x8 Hl1 = hdB[1][1][l];                      \
        f32x4 a = {bhc,bhc,bhc,bhc}, b = {0.f,0.f,0.f,0.f};                      \
        a = __builtin_amdgcn_mfma_f32_16x16x32_f16(FAh0, Hh0, a, 0,0,0);         \
        a = __builtin_amdgcn_mfma_f32_16x16x32_f16(FAh1, Hh1, a, 0,0,0);         \
        b = __builtin_amdgcn_mfma_f32_16x16x32_f16(FAh0, Hl0, b, 0,0,0);         \
        b = __builtin_amdgcn_mfma_f32_16x16x32_f16(FAl0, Hh0, b, 0,0,0);         \
        b = __builtin_amdgcn_mfma_f32_16x16x32_f16(FAh1, Hl1, b, 0,0,0);         \
        b = __builtin_amdgcn_mfma_f32_16x16x32_f16(FAl1, Hh1, b, 0,0,0);         \
        _Pragma("unroll")                                                        \
        for (int r = 0; r < 4; ++r) {                                            \
            float fv = __builtin_fmaf(INV2K, b[r], a[r]);                        \
            zreg[r][0] = __builtin_fmaf(dtv, bpermf(sa0, fv), zreg[r][0]);       \
            zreg[r][1] = __builtin_fmaf(dtv, bpermf(sa1, fv), zreg[r][1]);       \
            zreg[r][2] = __builtin_fmaf(dtv, bpermf(sa2, fv), zreg[r][2]);       \
        }                                                                        \
        ZSTORE();                                                                \
    }                                                                            \
    f32x4 gr0, gr1, gr2;                                                         \
    GATE(0, gr0, br); GATE(1, gr1, bu); GATE(2, gr2, bhn);                       \
    _Pragma("unroll")                                                            \
    for (int r = 0; r < 4; ++r) {                                                \
        float z0v = zreg[r][0], z1v = zreg[r][1], z2v = zreg[r][2];              \
        float ar  = __builtin_fmaf(wA[0], z0v, __builtin_fmaf(wA[1], z1v,        \
                    __builtin_fmaf(wA[2], z2v, gr0[r])));                        \
        float au  = __builtin_fmaf(wA[3], z0v, __builtin_fmaf(wB[0], z1v,        \
                    __builtin_fmaf(wB[1], z2v, gr1[r])));                        \
        float ain = __builtin_fmaf(wB[2], z0v, __builtin_fmaf(wB[3], z1v,        \
                    __builtin_fmaf(wC, z2v, bin_)));                             \
        float rg  = __builtin_amdgcn_rcpf(1.f + __builtin_amdgcn_exp2f(-ar));    \
        float ug_ = __builtin_amdgcn_rcpf(1.f + __builtin_amdgcn_exp2f(-au));    \
        float xs  = __builtin_fmaf(rg, gr2[r], ain);                             \
        float ng  = __builtin_fmaf(-2.f,                                         \
            __builtin_amdgcn_rcpf(1.f + __builtin_amdgcn_exp2f(xs)), 1.f);       \
        float hn  = __builtin_fmaf(ug_, hC[r] - ng, ng);                         \
        hC[r] = hn;                                                              \
        _Float16 hi = (_Float16)hn;                                              \
        _Float16 lo = (_Float16)((hn - (float)hi) * SC2K);                       \
        hbuf[(P)^1][0][adW + r*HS] = hi;                                         \
        hbuf[(P)^1][1][adW + r*HS] = lo;                                         \
    }                                                                            \
    LDS_BARRIER();                                                               \
} while (0)

    // ---- main loop: peel t=0, then pairs (compile-time ping-pong) ----
    STEP(0, false);
    int t = 1;
    for (; t + 1 < nsteps; t += 2) {
        STEP(1, true);
        STEP(0, true);
    }
    if (t < nsteps) { STEP(1, true); ++t; }

    // ---- epilogue: z(nsteps) from head over h(nsteps) ----
    {
        const int P = nsteps & 1;
        f16x8 FAh0 = *(const f16x8*)&hbuf[P][0][adA0];
        f16x8 FAh1 = *(const f16x8*)&hbuf[P][0][adA0 + 32];
        f16x8 FAl0 = *(const f16x8*)&hbuf[P][1][adA0];
        f16x8 FAl1 = *(const f16x8*)&hbuf[P][1][adA0 + 32];
        f16x8 Hh0 = hdB[0][0][l]; f16x8 Hh1 = hdB[0][1][l];
        f16x8 Hl0 = hdB[1][0][l]; f16x8 Hl1 = hdB[1][1][l];
        f32x4 a = {bhc,bhc,bhc,bhc}, b = {0.f,0.f,0.f,0.f};
        a = __builtin_amdgcn_mfma_f32_16x16x32_f16(FAh0, Hh0, a, 0,0,0);
        a = __builtin_amdgcn_mfma_f32_16x16x32_f16(FAh1, Hh1, a, 0,0,0);
        b = __builtin_amdgcn_mfma_f32_16x16x32_f16(FAh0, Hl0, b, 0,0,0);
        b = __builtin_amdgcn_mfma_f32_16x16x32_f16(FAl0, Hh0, b, 0,0,0);
        b = __builtin_amdgcn_mfma_f32_16x16x32_f16(FAh1, Hl1, b, 0,0,0);
        b = __builtin_amdgcn_mfma_f32_16x16x32_f16(FAl1, Hh1, b, 0,0,0);
        #pragma unroll
        for (int r = 0; r < 4; ++r) {
            float fv = __builtin_fmaf(INV2K, b[r], a[r]);
            zreg[r][0] = __builtin_fmaf(dtv, bpermf(sa0, fv), zreg[r][0]);
            zreg[r][1] = __builtin_fmaf(dtv, bpermf(sa1, fv), zreg[r][1]);
            zreg[r][2] = __builtin_fmaf(dtv, bpermf(sa2, fv), zreg[r][2]);
        }
        ZSTORE();
    }
#undef STEP
#undef GATE
#undef ZSTORE
}

extern "C" void kernel_launch(void* const* d_in, const int* in_sizes, int n_in,
                              void* d_out, int out_size, void* d_ws, size_t ws_size,
                              hipStream_t stream) {
    const float* z0    = (const float*)d_in[0];
    const float* dtp   = (const float*)d_in[1];
    const int*   steps = (const int*)  d_in[2];
    const float* Wih   = (const float*)d_in[3];
    const float* Whh   = (const float*)d_in[4];
    const float* bih   = (const float*)d_in[5];
    const float* bhh   = (const float*)d_in[6];
    const float* Whead = (const float*)d_in[7];
    const float* bhead = (const float*)d_in[8];
    float* out = (float*)d_out;

    const int B = in_sizes[0] / 3;          // 16384
    const int nblk = B / MELEM;             // 1024 blocks x 256 threads

    hipLaunchKernelGGL(gru_mfma_kernel, dim3(nblk), dim3(256), 0, stream,
                       z0, dtp, steps, Wih, Whh, bih, bhh, Whead, bhead, out);
}

// Round 18
// 3432.092 us; speedup vs baseline: 1.3989x; 1.3989x over previous
//
#include <hip/hip_runtime.h>

typedef _Float16 f16x8 __attribute__((ext_vector_type(8)));
typedef float f32x4 __attribute__((ext_vector_type(4)));

#define LOG2E 1.44269504088896340736f
#define MELEM 16          // batch elems per block (1 M-tile of 16)
#define HS 72             // f16 stride of h LDS rows (16B-aligned, bank-spread)
#define INV2K 4.8828125e-4f   // 2^-11
#define SC2K  2048.0f         // 2^11

__device__ __forceinline__ float bpermf(int sa, float v) {
    return __builtin_bit_cast(float,
        __builtin_amdgcn_ds_bpermute(sa, __builtin_bit_cast(int, v)));
}

// barrier that waits ONLY on LDS (lgkm), not on in-flight global traj stores
#define LDS_BARRIER() asm volatile("s_waitcnt lgkmcnt(0)\n\ts_barrier" ::: "memory")

// R16 structure; h stored as plain fp16 (no lo split) — W_hh/W_head keep the
// 2-way split so weight quantization stays ~fp32; z stays fp32 in regs.
__global__ __launch_bounds__(256, 2)
void gru_mfma_kernel(const float* __restrict__ z0,
                     const float* __restrict__ dtp,
                     const int* __restrict__ stepsp,
                     const float* __restrict__ Wih,
                     const float* __restrict__ Whh,
                     const float* __restrict__ bih,
                     const float* __restrict__ bhh,
                     const float* __restrict__ Whead,
                     const float* __restrict__ bhead,
                     float* __restrict__ out)
{
    // [pingpong][elem*HS + unit], plain fp16 h  (4608 B)
    __shared__ _Float16 hbuf[2][MELEM*HS];

    const int tid = threadIdx.x;
    const int w   = tid >> 6;       // wave 0..3 = unit group
    const int l   = tid & 63;
    const int c16 = l & 15;
    const int g   = l >> 4;         // 0..3
    const int unit = 16*w + c16;

    const float dtv = dtp[0];
    const int nsteps = stepsp[0];
    const size_t T3 = (size_t)(nsteps + 1) * 3;
    const long blk = blockIdx.x;

    // ---- B-fragments of W_hh: fp16 hi + 2^11-scaled lo, LOG2E-prescaled ----
    f16x8 WBh[3][2], WBl[3][2];
    #pragma unroll
    for (int gate = 0; gate < 3; ++gate) {
        const float gs = (gate == 2) ? 2.f*LOG2E : LOG2E;
        const float* row = Whh + (size_t)(gate*64 + unit) * 64;
        #pragma unroll
        for (int kk = 0; kk < 2; ++kk) {
            const float* p = row + 32*kk + 8*g;
            f16x8 bh_, bl_;
            #pragma unroll
            for (int j = 0; j < 8; ++j) {
                float x = gs * p[j];
                _Float16 hi = (_Float16)x;
                bh_[j] = hi;
                bl_[j] = (_Float16)((x - (float)hi) * SC2K);
            }
            WBh[gate][kk] = bh_;
            WBl[gate][kk] = bl_;
        }
    }
    // ---- head B-fragments in regs (cols >= 3 zero), plain scale ----
    f16x8 HBh[2], HBl[2];
    {
        f16x8 zf = {0,0,0,0,0,0,0,0};
        HBh[0]=zf; HBh[1]=zf; HBl[0]=zf; HBl[1]=zf;
        if (c16 < 3) {
            #pragma unroll
            for (int kk = 0; kk < 2; ++kk) {
                const float* p = Whead + (size_t)c16*64 + 32*kk + 8*g;
                f16x8 bh_, bl_;
                #pragma unroll
                for (int j = 0; j < 8; ++j) {
                    float x = p[j];
                    _Float16 hi = (_Float16)x;
                    bh_[j] = hi;
                    bl_[j] = (_Float16)((x - (float)hi) * SC2K);
                }
                HBh[kk] = bh_; HBl[kk] = bl_;
            }
        }
    }

    // ---- per-lane scalar weights / biases (prescaled) ----
    const float wir0 = LOG2E*Wih[(0*64+unit)*3+0], wir1 = LOG2E*Wih[(0*64+unit)*3+1], wir2 = LOG2E*Wih[(0*64+unit)*3+2];
    const float wiu0 = LOG2E*Wih[(1*64+unit)*3+0], wiu1 = LOG2E*Wih[(1*64+unit)*3+1], wiu2 = LOG2E*Wih[(1*64+unit)*3+2];
    const float win0 = 2.f*LOG2E*Wih[(2*64+unit)*3+0], win1 = 2.f*LOG2E*Wih[(2*64+unit)*3+1], win2 = 2.f*LOG2E*Wih[(2*64+unit)*3+2];
    const float br   = LOG2E*(bih[0*64+unit] + bhh[0*64+unit]);
    const float bu   = LOG2E*(bih[1*64+unit] + bhh[1*64+unit]);
    const float bin_ = 2.f*LOG2E*bih[2*64+unit];
    const float bhn  = 2.f*LOG2E*bhh[2*64+unit];
    float bhc = 0.f;
    if (c16 < 3) bhc = bhead[c16];

    // ---- z for the block's 16-elem tile, replicated across all lanes ----
    float zreg[4][3];
    #pragma unroll
    for (int r = 0; r < 4; ++r)
        #pragma unroll
        for (int c = 0; c < 3; ++c)
            zreg[r][c] = z0[(size_t)(blk*MELEM + 4*g + r)*3 + c];

    // ---- persistent traj cursors (designated: wave 0, c16<3) ----
    float* o0 = out; float* o1 = out; float* o2 = out; float* o3 = out;
    if (w == 0 && c16 < 3) {
        size_t e0 = (size_t)(blk*MELEM + 4*g);
        o0 = out + (e0+0)*T3 + c16;
        o1 = out + (e0+1)*T3 + c16;
        o2 = out + (e0+2)*T3 + c16;
        o3 = out + (e0+3)*T3 + c16;
    }
    // t=0 row
    #pragma unroll
    for (int c = 0; c < 3; ++c)
        if (w == 0 && c16 == c) {
            o0[0] = zreg[0][c]; o1[0] = zreg[1][c];
            o2[0] = zreg[2][c]; o3[0] = zreg[3][c];
        }
    if (w == 0 && c16 < 3) { o0 += 3; o1 += 3; o2 += 3; o3 += 3; }  // -> t=1

    // hoisted bpermute byte-addresses
    const int sa0 = (l & 48) << 2;
    const int sa1 = sa0 + 4;
    const int sa2 = sa0 + 8;

    // step-invariant LDS element offsets
    const int adA0 = c16*HS + 8*g;           // A-frag read row
    const int adW  = (4*g)*HS + unit;        // h write base (+ r*HS)

    // ---- zero h buffer 0 (h_0 = 0): 576 dwords ----
    {
        uint* hz = (uint*)&hbuf[0][0];
        for (int i = tid; i < (MELEM*HS)/2; i += 256) hz[i] = 0u;
    }

    float hC[4] = {0.f,0.f,0.f,0.f};

    __syncthreads();

#define GATE(GT, GR, BIAS) do {                                                  \
    f32x4 a1 = {BIAS,BIAS,BIAS,BIAS}, a2 = {0.f,0.f,0.f,0.f};                    \
    a1 = __builtin_amdgcn_mfma_f32_16x16x32_f16(FAh0, WBh[GT][0], a1, 0,0,0);    \
    a2 = __builtin_amdgcn_mfma_f32_16x16x32_f16(FAh0, WBl[GT][0], a2, 0,0,0);    \
    a1 = __builtin_amdgcn_mfma_f32_16x16x32_f16(FAh1, WBh[GT][1], a1, 0,0,0);    \
    a2 = __builtin_amdgcn_mfma_f32_16x16x32_f16(FAh1, WBl[GT][1], a2, 0,0,0);    \
    _Pragma("unroll")                                                            \
    for (int rr = 0; rr < 4; ++rr) GR[rr] = __builtin_fmaf(INV2K, a2[rr], a1[rr]); \
} while (0)

#define STEP(P, DOZ) do {                                                        \
    f16x8 FAh0 = *(const f16x8*)&hbuf[P][adA0];                                  \
    f16x8 FAh1 = *(const f16x8*)&hbuf[P][adA0 + 32];                             \
    if (DOZ) {                                                                   \
        f32x4 a = {bhc,bhc,bhc,bhc}, b = {0.f,0.f,0.f,0.f};                      \
        a = __builtin_amdgcn_mfma_f32_16x16x32_f16(FAh0, HBh[0], a, 0,0,0);      \
        a = __builtin_amdgcn_mfma_f32_16x16x32_f16(FAh1, HBh[1], a, 0,0,0);      \
        b = __builtin_amdgcn_mfma_f32_16x16x32_f16(FAh0, HBl[0], b, 0,0,0);      \
        b = __builtin_amdgcn_mfma_f32_16x16x32_f16(FAh1, HBl[1], b, 0,0,0);      \
        _Pragma("unroll")                                                        \
        for (int r = 0; r < 4; ++r) {                                            \
            float fv = __builtin_fmaf(INV2K, b[r], a[r]);                        \
            zreg[r][0] = __builtin_fmaf(dtv, bpermf(sa0, fv), zreg[r][0]);       \
            zreg[r][1] = __builtin_fmaf(dtv, bpermf(sa1, fv), zreg[r][1]);       \
            zreg[r][2] = __builtin_fmaf(dtv, bpermf(sa2, fv), zreg[r][2]);       \
        }                                                                        \
        _Pragma("unroll")                                                        \
        for (int c = 0; c < 3; ++c)                                              \
            if (w == 0 && c16 == c) {                                            \
                o0[0] = zreg[0][c]; o1[0] = zreg[1][c];                          \
                o2[0] = zreg[2][c]; o3[0] = zreg[3][c];                          \
            }                                                                    \
        if (w == 0 && c16 < 3) { o0 += 3; o1 += 3; o2 += 3; o3 += 3; }           \
    }                                                                            \
    f32x4 gr0, gr1, gr2;                                                         \
    GATE(0, gr0, br); GATE(1, gr1, bu); GATE(2, gr2, bhn);                       \
    _Pragma("unroll")                                                            \
    for (int r = 0; r < 4; ++r) {                                                \
        float z0v = zreg[r][0], z1v = zreg[r][1], z2v = zreg[r][2];              \
        float ar  = __builtin_fmaf(wir0, z0v, __builtin_fmaf(wir1, z1v,          \
                    __builtin_fmaf(wir2, z2v, gr0[r])));                         \
        float au  = __builtin_fmaf(wiu0, z0v, __builtin_fmaf(wiu1, z1v,          \
                    __builtin_fmaf(wiu2, z2v, gr1[r])));                         \
        float ain = __builtin_fmaf(win0, z0v, __builtin_fmaf(win1, z1v,          \
                    __builtin_fmaf(win2, z2v, bin_)));                           \
        float rg  = __builtin_amdgcn_rcpf(1.f + __builtin_amdgcn_exp2f(-ar));    \
        float ug_ = __builtin_amdgcn_rcpf(1.f + __builtin_amdgcn_exp2f(-au));    \
        float xs  = __builtin_fmaf(rg, gr2[r], ain);                             \
        float ng  = __builtin_fmaf(-2.f,                                         \
            __builtin_amdgcn_rcpf(1.f + __builtin_amdgcn_exp2f(xs)), 1.f);       \
        float hn  = __builtin_fmaf(ug_, hC[r] - ng, ng);                         \
        hC[r] = hn;                                                              \
        hbuf[(P)^1][adW + r*HS] = (_Float16)hn;                                  \
    }                                                                            \
    LDS_BARRIER();                                                               \
} while (0)

    // ---- main loop: peel t=0, then pairs (compile-time ping-pong) ----
    STEP(0, false);
    int t = 1;
    for (; t + 1 < nsteps; t += 2) {
        STEP(1, true);
        STEP(0, true);
    }
    if (t < nsteps) { STEP(1, true); ++t; }

    // ---- epilogue: z(nsteps) from head over h(nsteps) ----
    {
        const int P = nsteps & 1;
        f16x8 FAh0 = *(const f16x8*)&hbuf[P][adA0];
        f16x8 FAh1 = *(const f16x8*)&hbuf[P][adA0 + 32];
        f32x4 a = {bhc,bhc,bhc,bhc}, b = {0.f,0.f,0.f,0.f};
        a = __builtin_amdgcn_mfma_f32_16x16x32_f16(FAh0, HBh[0], a, 0,0,0);
        a = __builtin_amdgcn_mfma_f32_16x16x32_f16(FAh1, HBh[1], a, 0,0,0);
        b = __builtin_amdgcn_mfma_f32_16x16x32_f16(FAh0, HBl[0], b, 0,0,0);
        b = __builtin_amdgcn_mfma_f32_16x16x32_f16(FAh1, HBl[1], b, 0,0,0);
        #pragma unroll
        for (int r = 0; r < 4; ++r) {
            float fv = __builtin_fmaf(INV2K, b[r], a[r]);
            zreg[r][0] = __builtin_fmaf(dtv, bpermf(sa0, fv), zreg[r][0]);
            zreg[r][1] = __builtin_fmaf(dtv, bpermf(sa1, fv), zreg[r][1]);
            zreg[r][2] = __builtin_fmaf(dtv, bpermf(sa2, fv), zreg[r][2]);
        }
        #pragma unroll
        for (int c = 0; c < 3; ++c)
            if (w == 0 && c16 == c) {
                o0[0] = zreg[0][c]; o1[0] = zreg[1][c];
                o2[0] = zreg[2][c]; o3[0] = zreg[3][c];
            }
    }
#undef STEP
#undef GATE
}

extern "C" void kernel_launch(void* const* d_in, const int* in_sizes, int n_in,
                              void* d_out, int out_size, void* d_ws, size_t ws_size,
                              hipStream_t stream) {
    const float* z0    = (const float*)d_in[0];
    const float* dtp   = (const float*)d_in[1];
    const int*   steps = (const int*)  d_in[2];
    const float* Wih   = (const float*)d_in[3];
    const float* Whh   = (const float*)d_in[4];
    const float* bih   = (const float*)d_in[5];
    const float* bhh   = (const float*)d_in[6];
    const float* Whead = (const float*)d_in[7];
    const float* bhead = (const float*)d_in[8];
    float* out = (float*)d_out;

    const int B = in_sizes[0] / 3;          // 16384
    const int nblk = B / MELEM;             // 1024 blocks x 256 threads

    hipLaunchKernelGGL(gru_mfma_kernel, dim3(nblk), dim3(256), 0, stream,
                       z0, dtp, steps, Wih, Whh, bih, bhh, Whead, bhead, out);
}